// Round 2
// baseline (53.946 us; speedup 1.0000x reference)
//
#include <hip/hip_runtime.h>

// SKA: out[n, g*CW+cw, h, w] = sum_{a,b in 0..2} x[n, g*CW+cw, h+a-1, w+b-1] * w[n, cw, a*3+b, h, w]
// x: (8, 256, 96, 96) f32 ; w: (8, 32, 9, 96, 96) f32 ; out: (8, 256, 96, 96) f32
// Memory-bound: ideal traffic 236 MB -> ~37us @ 6.3 TB/s.

#define N_  8
#define C_  256
#define H_  96
#define W_  96
#define CW_ 32
#define G_  8

__global__ __launch_bounds__(256) void SKA_kernel(const float* __restrict__ x,
                                                  const float* __restrict__ wgt,
                                                  float* __restrict__ out) {
    constexpr int W4 = W_ / 4;  // 24 float4s per row
    const int tid = blockIdx.x * blockDim.x + threadIdx.x;
    constexpr int total = N_ * CW_ * H_ * W4;  // 589824 threads
    if (tid >= total) return;

    const int tw = tid % W4;
    const int t1 = tid / W4;
    const int h  = t1 % H_;
    const int t2 = t1 / H_;
    const int cw = t2 % CW_;
    const int n  = t2 / CW_;
    const int w0 = tw * 4;

    constexpr size_t PLANE = (size_t)H_ * W_;  // 9216

    float acc[G_][4];
#pragma unroll
    for (int g = 0; g < G_; ++g)
#pragma unroll
        for (int j = 0; j < 4; ++j) acc[g][j] = 0.f;

    // w base for k=0: (((n*CW + cw)*9 + k)*H + h)*W + w0
    const float* wbase = wgt + ((((size_t)n * CW_ + cw) * 9) * H_ + (size_t)h) * W_ + w0;
    // x base channel cw (add g*CW_*PLANE per group)
    const float* xbase = x + ((size_t)n * C_ + cw) * PLANE;

#pragma unroll
    for (int a = 0; a < 3; ++a) {
        const int hh = h + a - 1;
        if (hh < 0 || hh >= H_) continue;  // zero padding: contributes nothing

        // per-pixel kernel taps for this row of the 3x3 window (aligned float4 loads)
        float wv[3][4];
#pragma unroll
        for (int b = 0; b < 3; ++b) {
            const float4 v = *reinterpret_cast<const float4*>(wbase + (size_t)(a * 3 + b) * PLANE);
            wv[b][0] = v.x; wv[b][1] = v.y; wv[b][2] = v.z; wv[b][3] = v.w;
        }

#pragma unroll
        for (int g = 0; g < G_; ++g) {
            const float* xr = xbase + (size_t)g * CW_ * PLANE + (size_t)hh * W_ + w0;
            float xrow[6];
            xrow[0] = (w0 > 0) ? xr[-1] : 0.f;
            xrow[1] = xr[0];
            xrow[2] = xr[1];
            xrow[3] = xr[2];
            xrow[4] = xr[3];
            xrow[5] = (w0 + 4 < W_) ? xr[4] : 0.f;
#pragma unroll
            for (int b = 0; b < 3; ++b) {
#pragma unroll
                for (int j = 0; j < 4; ++j) {
                    acc[g][j] = fmaf(xrow[j + b], wv[b][j], acc[g][j]);
                }
            }
        }
    }

    float* obase = out + ((size_t)n * C_ + cw) * PLANE + (size_t)h * W_ + w0;
#pragma unroll
    for (int g = 0; g < G_; ++g) {
        *reinterpret_cast<float4*>(obase + (size_t)g * CW_ * PLANE) =
            make_float4(acc[g][0], acc[g][1], acc[g][2], acc[g][3]);
    }
}

extern "C" void kernel_launch(void* const* d_in, const int* in_sizes, int n_in,
                              void* d_out, int out_size, void* d_ws, size_t ws_size,
                              hipStream_t stream) {
    const float* x   = (const float*)d_in[0];
    const float* wgt = (const float*)d_in[1];
    float* out = (float*)d_out;

    constexpr int total  = N_ * CW_ * H_ * (W_ / 4);  // 589824
    constexpr int block  = 256;
    constexpr int grid   = (total + block - 1) / block;  // 2304
    SKA_kernel<<<grid, block, 0, stream>>>(x, wgt, out);
}

// Round 3
// 51.685 us; speedup vs baseline: 1.0437x; 1.0437x over previous
//
#include <hip/hip_runtime.h>

// SKA: out[n, g*CW+cw, h, w] = sum_{a,b in 0..2} x[n, g*CW+cw, h+a-1, w+b-1] * w[n, cw, a*3+b, h, w]
// x: (8, 256, 96, 96) f32 ; w: (8, 32, 9, 96, 96) f32 ; out: (8, 256, 96, 96) f32
// Round 2: LDS-staged x (vectorized global loads), w hoisted pre-barrier, halo via LDS.

#define N_  8
#define C_  256
#define H_  96
#define W_  96
#define CW_ 32
#define G_  8
#define R_  8           // output rows per block
#define RH_ (R_ + 2)    // staged rows (with halo)
#define P_  100         // LDS row pitch in floats (multiple of 4; 400B row base stays 16B-aligned)
#define TB_ 192         // 24 w4-positions x 8 rows

// LDS column map: col 4+w = x[w] (w=0..95); cols 0..3 = 0 (left halo at col 3);
// col 100 of row rho = col 0 of row rho+1 = 0 (right halo); pad 4 floats for last row.

__global__ __launch_bounds__(TB_) void SKA_kernel(const float* __restrict__ x,
                                                  const float* __restrict__ wgt,
                                                  float* __restrict__ out) {
    __shared__ float xs[G_ * RH_ * P_ + 4];

    constexpr size_t PLANE = (size_t)H_ * W_;  // 9216

    const int blk = blockIdx.x;
    const int ht  = blk % (H_ / R_);
    const int t1  = blk / (H_ / R_);
    const int cw  = t1 % CW_;
    const int n   = t1 / CW_;
    const int h0  = ht * R_;

    const int tid = threadIdx.x;
    const int w4  = tid % 24;
    const int r   = tid / 24;      // 0..7
    const int w0  = w4 * 4;
    const int h   = h0 + r;

    // ---- hoist the 9 per-pixel w taps (global, reused across all 8 groups) ----
    const float* wb = wgt + (((size_t)(n * CW_ + cw) * 9) * H_ + (size_t)h) * W_ + w0;
    float wv[9][4];
#pragma unroll
    for (int k = 0; k < 9; ++k) {
        const float4 v = *reinterpret_cast<const float4*>(wb + (size_t)k * PLANE);
        wv[k][0] = v.x; wv[k][1] = v.y; wv[k][2] = v.z; wv[k][3] = v.w;
    }

    // ---- stage x into LDS (float4 loads only) ----
    // slots: g(8) x rho(10) x w4c(25); w4c==0 -> zero vec4 at cols 0..3, else data at cols 4*w4c..+3
    constexpr int SLOTS = G_ * RH_ * 25;  // 2000
    const float* xn = x + (size_t)n * C_ * PLANE;
#pragma unroll 1
    for (int i = tid; i < SLOTS; i += TB_) {
        const int w4c = i % 25;
        const int rho = (i / 25) % RH_;
        const int g   = i / (25 * RH_);
        float4 v = make_float4(0.f, 0.f, 0.f, 0.f);
        const int hh = h0 + rho - 1;
        if (w4c > 0 && hh >= 0 && hh < H_) {
            v = *reinterpret_cast<const float4*>(
                    xn + (size_t)(g * CW_ + cw) * PLANE + (size_t)hh * W_ + (w4c - 1) * 4);
        }
        *reinterpret_cast<float4*>(&xs[(g * RH_ + rho) * P_ + w4c * 4]) = v;
    }
    if (tid < 4) xs[G_ * RH_ * P_ + tid] = 0.f;  // pad past last row (right halo of row 9)
    __syncthreads();

    // ---- compute ----
    float acc[G_][4];
#pragma unroll
    for (int g = 0; g < G_; ++g)
#pragma unroll
        for (int j = 0; j < 4; ++j) acc[g][j] = 0.f;

#pragma unroll
    for (int a = 0; a < 3; ++a) {
#pragma unroll
        for (int g = 0; g < G_; ++g) {
            const float* row = &xs[(g * RH_ + (r + a)) * P_];
            const float4 xm = *reinterpret_cast<const float4*>(row + 4 + w0);  // x[w0..w0+3]
            const float  xl = row[3 + w0];                                     // x[w0-1]
            const float  xr = row[8 + w0];                                     // x[w0+4]
            const float xv[6] = {xl, xm.x, xm.y, xm.z, xm.w, xr};
#pragma unroll
            for (int bb = 0; bb < 3; ++bb) {
#pragma unroll
                for (int j = 0; j < 4; ++j) {
                    acc[g][j] = fmaf(xv[bb + j], wv[a * 3 + bb][j], acc[g][j]);
                }
            }
        }
    }

    float* ob = out + ((size_t)n * C_ + cw) * PLANE + (size_t)h * W_ + w0;
#pragma unroll
    for (int g = 0; g < G_; ++g) {
        *reinterpret_cast<float4*>(ob + (size_t)g * CW_ * PLANE) =
            make_float4(acc[g][0], acc[g][1], acc[g][2], acc[g][3]);
    }
}

extern "C" void kernel_launch(void* const* d_in, const int* in_sizes, int n_in,
                              void* d_out, int out_size, void* d_ws, size_t ws_size,
                              hipStream_t stream) {
    const float* x   = (const float*)d_in[0];
    const float* wgt = (const float*)d_in[1];
    float* out = (float*)d_out;

    constexpr int grid = N_ * CW_ * (H_ / R_);  // 3072 blocks
    SKA_kernel<<<grid, TB_, 0, stream>>>(x, wgt, out);
}

// Round 5
// 42.828 us; speedup vs baseline: 1.2596x; 1.2068x over previous
//
#include <hip/hip_runtime.h>

// SKA: out[n, g*CW+cw, h, w] = sum_{a,b in 0..2} x[n, g*CW+cw, h+a-1, w+b-1] * w[n, cw, a*3+b, h, w]
// x: (8, 256, 96, 96) f32 ; w: (8, 32, 9, 96, 96) f32 ; out: (8, 256, 96, 96) f32
// Round 4: Round-3 design (no LDS, no barriers, shfl halo) with native vector type
// so __builtin_nontemporal_store compiles (HIP float4 is a class, not a clang vector).

#define N_  8
#define C_  256
#define H_  96
#define W_  96
#define CW_ 32
#define G_  8

typedef float f32x4 __attribute__((ext_vector_type(4)));

__global__ __launch_bounds__(256, 4) void SKA_kernel(const float* __restrict__ x,
                                                     const float* __restrict__ wgt,
                                                     float* __restrict__ out) {
    constexpr size_t PLANE = (size_t)H_ * W_;  // 9216

    const int tid   = threadIdx.x;
    const int widx  = tid & 31;   // 0..31, 24 active (w0 = 4*widx < 96)
    const int rowid = tid >> 5;   // 0..7
    const int lane  = tid & 63;   // lane within wave

    const int blk = blockIdx.x;
    const int ht  = blk % (H_ / 8);
    const int t1  = blk / (H_ / 8);
    const int cw  = t1 % CW_;
    const int n   = t1 / CW_;
    const int h   = ht * 8 + rowid;
    const int w0  = widx * 4;

    if (widx >= 24) return;  // padded lanes (96 = 24 float4s per row)

    // ---- 9 per-pixel kernel taps, reused across all 8 groups ----
    const float* wb = wgt + (((size_t)(n * CW_ + cw) * 9) * H_ + (size_t)h) * W_ + w0;
    f32x4 wv[9];
#pragma unroll
    for (int k = 0; k < 9; ++k)
        wv[k] = *reinterpret_cast<const f32x4*>(wb + (size_t)k * PLANE);

    float acc[G_][4];
#pragma unroll
    for (int g = 0; g < G_; ++g)
#pragma unroll
        for (int j = 0; j < 4; ++j) acc[g][j] = 0.f;

    const float* xb = x + ((size_t)n * C_ + cw) * PLANE + w0;

#pragma unroll
    for (int a = 0; a < 3; ++a) {
        const int hh = h + a - 1;
        if (hh < 0 || hh >= H_) continue;  // zero padding rows
        const f32x4 w0v = wv[a * 3 + 0];
        const f32x4 w1v = wv[a * 3 + 1];
        const f32x4 w2v = wv[a * 3 + 2];
#pragma unroll
        for (int g = 0; g < G_; ++g) {
            const f32x4 xm = *reinterpret_cast<const f32x4*>(
                xb + (size_t)(g * CW_) * PLANE + (size_t)hh * W_);
            // halo via cross-lane exchange (lane stride 1 == 4 floats in w)
            float xl = __shfl(xm.w, lane - 1);
            float xr = __shfl(xm.x, lane + 1);
            xl = (widx == 0) ? 0.f : xl;   // x[-1] pad
            xr = (widx == 23) ? 0.f : xr;  // x[96] pad
            // out[j] += sum_b x[w0+j+b-1] * wt[b][j]
            acc[g][0] = fmaf(xl,   w0v.x, acc[g][0]);
            acc[g][0] = fmaf(xm.x, w1v.x, acc[g][0]);
            acc[g][0] = fmaf(xm.y, w2v.x, acc[g][0]);
            acc[g][1] = fmaf(xm.x, w0v.y, acc[g][1]);
            acc[g][1] = fmaf(xm.y, w1v.y, acc[g][1]);
            acc[g][1] = fmaf(xm.z, w2v.y, acc[g][1]);
            acc[g][2] = fmaf(xm.y, w0v.z, acc[g][2]);
            acc[g][2] = fmaf(xm.z, w1v.z, acc[g][2]);
            acc[g][2] = fmaf(xm.w, w2v.z, acc[g][2]);
            acc[g][3] = fmaf(xm.z, w0v.w, acc[g][3]);
            acc[g][3] = fmaf(xm.w, w1v.w, acc[g][3]);
            acc[g][3] = fmaf(xr,   w2v.w, acc[g][3]);
        }
    }

    float* ob = out + ((size_t)n * C_ + cw) * PLANE + (size_t)h * W_ + w0;
#pragma unroll
    for (int g = 0; g < G_; ++g) {
        f32x4 v;
        v.x = acc[g][0]; v.y = acc[g][1]; v.z = acc[g][2]; v.w = acc[g][3];
        __builtin_nontemporal_store(v, reinterpret_cast<f32x4*>(ob + (size_t)(g * CW_) * PLANE));
    }
}

extern "C" void kernel_launch(void* const* d_in, const int* in_sizes, int n_in,
                              void* d_out, int out_size, void* d_ws, size_t ws_size,
                              hipStream_t stream) {
    const float* x   = (const float*)d_in[0];
    const float* wgt = (const float*)d_in[1];
    float* out = (float*)d_out;

    constexpr int grid = N_ * CW_ * (H_ / 8);  // 3072 blocks x 256 threads
    SKA_kernel<<<grid, 256, 0, stream>>>(x, wgt, out);
}